// Round 8
// baseline (86.703 us; speedup 1.0000x reference)
//
#include <hip/hip_runtime.h>
#include <math.h>

#define BB 4
#define CC 19
#define NPIX (512 * 1024)       // 524288 per image
#define NB 80                   // histogram bins over max_prob in [0,1]
#define CONF_BIN 72             // 0.9 * 80 exactly -> bin>=72 <=> p>=0.9
#define FRACTION_F 0.66f
#define ROW (CC * NB)           // 1520
#define NROW (BB * CC)          // 76

#define NBLK1 1024
#define BPI (NBLK1 / BB)        // 256 blocks per image
#define SEG (NPIX / BPI)        // 2048 px per block
#define T1 256                  // 4 waves/block; 6 blocks/CU -> 24 waves/CU

// ws layout:
//   int   cntPart[NBLK1][ROW]   (6.2 MB)
//   float snlPart[NBLK1][ROW]   (6.2 MB)

static __device__ __forceinline__ float comp(float4 v, int j) {
    return (j == 0) ? v.x : (j == 1) ? v.y : (j == 2) ? v.z : v.w;
}

__global__ __launch_bounds__(T1, 6) void st_pass1(const float* __restrict__ pred,
                                                  int* __restrict__ cntPart,
                                                  float* __restrict__ snlPart,
                                                  float* __restrict__ out) {
    __shared__ int   hcnt[ROW];
    __shared__ float hsnl[ROW];
    int tid = threadIdx.x;
    if (blockIdx.x == 0 && tid == 0) out[0] = 0.f;   // pass2 accumulates atomically
    for (int i = tid; i < ROW; i += T1) { hcnt[i] = 0; hsnl[i] = 0.f; }
    __syncthreads();

    int blk = blockIdx.x;
    int b   = blk >> 8;                  // / BPI
    int seg = blk & (BPI - 1);
    const float* bp0 = pred + (size_t)b * CC * NPIX + (size_t)seg * SEG + tid * 4;
    const float* bp1 = bp0 + T1 * 4;     // second half of this block's segment

    float4 va[5], vb[5], vc[5], vd[4];
    float m[4], s[4]; int arg[4];

#define LOAD5(DST, BP, C0)                                            \
        _Pragma("unroll")                                             \
        for (int i = 0; i < 5; ++i)                                   \
            DST[i] = *(const float4*)((BP) + (size_t)(C0 + i) * NPIX);
#define LOAD4(DST, BP, C0)                                            \
        _Pragma("unroll")                                             \
        for (int i = 0; i < 4; ++i)                                   \
            DST[i] = *(const float4*)((BP) + (size_t)(C0 + i) * NPIX);
#define FENCE asm volatile("" ::: "memory")
#define INIT4(VA)                                                     \
        _Pragma("unroll")                                             \
        for (int j = 0; j < 4; ++j) { m[j] = comp(VA[0], j); s[j] = 1.f; arg[j] = 0; }
#define PROC(VA, NCH, CBASE, START)                                   \
        _Pragma("unroll")                                             \
        for (int i = START; i < NCH; ++i) {                           \
            _Pragma("unroll")                                         \
            for (int j = 0; j < 4; ++j) {                             \
                float x  = comp(VA[i], j);                            \
                float nm = fmaxf(m[j], x);                            \
                s[j] = s[j] * __expf(m[j] - nm) + __expf(x - nm);     \
                arg[j] = (x > m[j]) ? (CBASE + i) : arg[j];           \
                m[j] = nm;                                            \
            }                                                         \
        }
#define FINAL()                                                       \
        _Pragma("unroll")                                             \
        for (int j = 0; j < 4; ++j) {                                 \
            float prob = 1.f / s[j];                                  \
            float nll  = __logf(s[j]);                                \
            int bin = min((int)(prob * (float)NB), NB - 1);           \
            int idx = arg[j] * NB + bin;                              \
            atomicAdd(&hcnt[idx], 1);                                 \
            atomicAdd(&hsnl[idx], nll);                               \
        }

    // 8-group rolling pipeline across BOTH iterations: loads never drain.
    LOAD5(va, bp0, 0); LOAD5(vb, bp0, 5); FENCE;
    INIT4(va)
    PROC(va, 5, 0, 1)
    LOAD5(vc, bp0, 10); FENCE;
    PROC(vb, 5, 5, 0)
    LOAD4(vd, bp0, 15); FENCE;
    PROC(vc, 5, 10, 0)
    LOAD5(va, bp1, 0); FENCE;            // prefetch iter2 g0 before last PROC
    PROC(vd, 4, 15, 0)
    FINAL()                              // iter1 atomics overlap iter2 loads
    LOAD5(vb, bp1, 5); FENCE;
    INIT4(va)
    PROC(va, 5, 0, 1)
    LOAD5(vc, bp1, 10); FENCE;
    PROC(vb, 5, 5, 0)
    LOAD4(vd, bp1, 15); FENCE;
    PROC(vc, 5, 10, 0)
    PROC(vd, 4, 15, 0)
    FINAL()
#undef LOAD5
#undef LOAD4
#undef FENCE
#undef INIT4
#undef PROC
#undef FINAL
    __syncthreads();

    // flush private slice with plain coalesced stores
    int*   cp = cntPart + (size_t)blk * ROW;
    float* sp = snlPart + (size_t)blk * ROW;
    for (int i = tid; i < ROW; i += T1) { cp[i] = hcnt[i]; sp[i] = hsnl[i]; }
}

// Fused tail: one block per (b,c) row. 4 threads per bin sum 64 partials each
// (coalesced), LDS combine, thread 0 scans for the rank cutoff and atomically
// adds the row's contribution to out[0] (zeroed by pass1).
__global__ __launch_bounds__(320) void st_pass2(const int* __restrict__ cntPart,
                                                const float* __restrict__ snlPart,
                                                float* __restrict__ out) {
    __shared__ int   pcnt[4][NB];
    __shared__ float psnl[4][NB];
    __shared__ int   scnt[NB];
    __shared__ float ssnl[NB];
    int r = blockIdx.x;                  // 0..75
    int b = r / CC, c = r - b * CC;
    int tid = threadIdx.x;

    if (tid < 4 * NB) {
        int q   = tid / NB;              // partial-quarter 0..3
        int bin = tid - q * NB;
        size_t off = (size_t)(b * BPI + q * 64) * ROW + (size_t)(c * NB + bin);
        int cs0 = 0, cs1 = 0; float ss0 = 0.f, ss1 = 0.f;
        #pragma unroll 8
        for (int p = 0; p < 64; p += 2) {
            cs0 += cntPart[off + (size_t)p * ROW];
            cs1 += cntPart[off + (size_t)(p + 1) * ROW];
            ss0 += snlPart[off + (size_t)p * ROW];
            ss1 += snlPart[off + (size_t)(p + 1) * ROW];
        }
        pcnt[q][bin] = cs0 + cs1;
        psnl[q][bin] = ss0 + ss1;
    }
    __syncthreads();
    if (tid < NB) {
        scnt[tid] = (pcnt[0][tid] + pcnt[1][tid]) + (pcnt[2][tid] + pcnt[3][tid]);
        ssnl[tid] = (psnl[0][tid] + psnl[1][tid]) + (psnl[2][tid] + psnl[3][tid]);
    }
    __syncthreads();

    if (tid == 0) {
        int count = 0;
        #pragma unroll 8
        for (int i = 0; i < NB; ++i) count += scnt[i];
        float conf = 0.f;                // sum of nll where p >= 0.9
        #pragma unroll 8
        for (int i = CONF_BIN; i < NB; ++i) conf += ssnl[i];
        int k = (int)floorf((float)count * FRACTION_F);  // match jnp f32 math
        float sel;
        if (k == 0) {
            sel = conf;
        } else {
            int cum = 0;                 // count in bins strictly above boundary
            float csum = 0.f;
            int bin = NB - 1;
            int hh = 0;
            for (; bin >= 0; --bin) {
                hh = scnt[bin];
                if (cum + hh >= k) break;    // rank k-1 lies in this bin
                cum += hh;
                csum += ssnl[bin];
            }
            if (bin < 0) {
                sel = csum;              // safety (k < count always)
            } else if (bin >= CONF_BIN) {
                sel = conf;              // cutoff >= 0.9 -> union == {p>0.9}
            } else {
                float avg = ssnl[bin] / (float)max(hh, 1);
                sel = csum + (float)(k - cum) * avg;
            }
        }
        atomicAdd(out, sel * (1.0f / (float)(BB * (size_t)NPIX)));
    }
}

extern "C" void kernel_launch(void* const* d_in, const int* in_sizes, int n_in,
                              void* d_out, int out_size, void* d_ws, size_t ws_size,
                              hipStream_t stream) {
    const float* pred = (const float*)d_in[0];
    float* out = (float*)d_out;

    char* ws = (char*)d_ws;
    int*   cntPart = (int*)ws;
    float* snlPart = (float*)(ws + (size_t)NBLK1 * ROW * sizeof(int));

    st_pass1<<<NBLK1, T1, 0, stream>>>(pred, cntPart, snlPart, out);
    st_pass2<<<NROW, 320, 0, stream>>>(cntPart, snlPart, out);
}

// Round 9
// 43.583 us; speedup vs baseline: 1.9894x; 1.9894x over previous
//
#include <hip/hip_runtime.h>
#include <math.h>

#define BB 4
#define CC 19
#define NPIX (512 * 1024)       // 524288 per image
#define NB 80                   // histogram bins over max_prob in [0,1]
#define CONF_BIN 72             // 0.9 * 80 exactly -> bin>=72 <=> p>=0.9
#define FRACTION_F 0.66f
#define ROW (CC * NB)           // 1520
#define NROW (BB * CC)          // 76

#define NBLK1 512
#define BPI (NBLK1 / BB)        // 128 blocks per image
#define PPB (NPIX / BPI)        // 4096 px per block
#define T1 512                  // 8 waves/block, 2 blocks/CU -> 16 waves/CU
// NOTE: launch_bounds(512,4) -> VGPR cap 128. The rolling pipeline needs
// ~100 VGPR; R8 proved a tighter cap (85) collapses it to 40 VGPR / no MLP.

typedef float f4 __attribute__((ext_vector_type(4)));

// ws layout:
//   int   cntPart[NBLK1][ROW]   (3.11 MB)
//   float snlPart[NBLK1][ROW]   (3.11 MB)

static __device__ __forceinline__ float comp(f4 v, int j) {
    return (j == 0) ? v.x : (j == 1) ? v.y : (j == 2) ? v.z : v.w;
}

__global__ __launch_bounds__(T1, 4) void st_pass1(const float* __restrict__ pred,
                                                  int* __restrict__ cntPart,
                                                  float* __restrict__ snlPart,
                                                  float* __restrict__ out) {
    __shared__ int   hcnt[ROW];
    __shared__ float hsnl[ROW];
    int tid = threadIdx.x;
    if (blockIdx.x == 0 && tid == 0) out[0] = 0.f;   // pass2 accumulates atomically
    for (int i = tid; i < ROW; i += T1) { hcnt[i] = 0; hsnl[i] = 0.f; }
    __syncthreads();

    int blk = blockIdx.x;
    int b   = blk >> 7;                  // / BPI
    int seg = blk & (BPI - 1);
    const float* bp0 = pred + (size_t)b * CC * NPIX + (size_t)seg * PPB + tid * 4;
    const float* bp1 = bp0 + T1 * 4;     // second half of this block's segment

    f4 va[5], vb[5], vc[5], vd[4];
    float m[4], s[4]; int arg[4];

// nontemporal: 160 MB streamed once -> tell L2 not to allocate
#define LOAD5(DST, BP, C0)                                            \
        _Pragma("unroll")                                             \
        for (int i = 0; i < 5; ++i)                                   \
            DST[i] = __builtin_nontemporal_load((const f4*)((BP) + (size_t)(C0 + i) * NPIX));
#define LOAD4(DST, BP, C0)                                            \
        _Pragma("unroll")                                             \
        for (int i = 0; i < 4; ++i)                                   \
            DST[i] = __builtin_nontemporal_load((const f4*)((BP) + (size_t)(C0 + i) * NPIX));
#define FENCE asm volatile("" ::: "memory")
#define INIT4(VA)                                                     \
        _Pragma("unroll")                                             \
        for (int j = 0; j < 4; ++j) { m[j] = comp(VA[0], j); s[j] = 1.f; arg[j] = 0; }
#define PROC(VA, NCH, CBASE, START)                                   \
        _Pragma("unroll")                                             \
        for (int i = START; i < NCH; ++i) {                           \
            _Pragma("unroll")                                         \
            for (int j = 0; j < 4; ++j) {                             \
                float x  = comp(VA[i], j);                            \
                float nm = fmaxf(m[j], x);                            \
                s[j] = s[j] * __expf(m[j] - nm) + __expf(x - nm);     \
                arg[j] = (x > m[j]) ? (CBASE + i) : arg[j];           \
                m[j] = nm;                                            \
            }                                                         \
        }
#define FINAL()                                                       \
        _Pragma("unroll")                                             \
        for (int j = 0; j < 4; ++j) {                                 \
            float prob = 1.f / s[j];                                  \
            float nll  = __logf(s[j]);                                \
            int bin = min((int)(prob * (float)NB), NB - 1);           \
            int idx = arg[j] * NB + bin;                              \
            atomicAdd(&hcnt[idx], 1);                                 \
            atomicAdd(&hsnl[idx], nll);                               \
        }

    // 8-group rolling pipeline across BOTH iterations: loads never drain.
    LOAD5(va, bp0, 0); LOAD5(vb, bp0, 5); FENCE;
    INIT4(va)
    PROC(va, 5, 0, 1)
    LOAD5(vc, bp0, 10); FENCE;
    PROC(vb, 5, 5, 0)
    LOAD4(vd, bp0, 15); FENCE;
    PROC(vc, 5, 10, 0)
    LOAD5(va, bp1, 0); FENCE;            // prefetch iter2 g0 before last PROC
    PROC(vd, 4, 15, 0)
    FINAL()                              // iter1 atomics overlap iter2 loads
    LOAD5(vb, bp1, 5); FENCE;
    INIT4(va)
    PROC(va, 5, 0, 1)
    LOAD5(vc, bp1, 10); FENCE;
    PROC(vb, 5, 5, 0)
    LOAD4(vd, bp1, 15); FENCE;
    PROC(vc, 5, 10, 0)
    PROC(vd, 4, 15, 0)
    FINAL()
#undef LOAD5
#undef LOAD4
#undef FENCE
#undef INIT4
#undef PROC
#undef FINAL
    __syncthreads();

    // flush private slice with plain coalesced stores
    int*   cp = cntPart + (size_t)blk * ROW;
    float* sp = snlPart + (size_t)blk * ROW;
    for (int i = tid; i < ROW; i += T1) { cp[i] = hcnt[i]; sp[i] = hsnl[i]; }
}

// Fused tail: one block per (b,c) row. 4 threads per bin sum 32 partials each
// (coalesced), LDS combine, thread 0 scans for the rank cutoff and atomically
// adds the row's contribution to out[0] (zeroed by pass1).
__global__ __launch_bounds__(384) void st_pass2(const int* __restrict__ cntPart,
                                                const float* __restrict__ snlPart,
                                                float* __restrict__ out) {
    __shared__ int   pcnt[4][NB];
    __shared__ float psnl[4][NB];
    __shared__ int   scnt[NB];
    __shared__ float ssnl[NB];
    int r = blockIdx.x;                  // 0..75
    int b = r / CC, c = r - b * CC;
    int tid = threadIdx.x;

    if (tid < 4 * NB) {
        int q   = tid / NB;              // partial-quarter 0..3
        int bin = tid - q * NB;
        size_t off = (size_t)(b * BPI + q * 32) * ROW + (size_t)(c * NB + bin);
        int cs0 = 0, cs1 = 0; float ss0 = 0.f, ss1 = 0.f;
        #pragma unroll 8
        for (int p = 0; p < 32; p += 2) {
            cs0 += cntPart[off + (size_t)p * ROW];
            cs1 += cntPart[off + (size_t)(p + 1) * ROW];
            ss0 += snlPart[off + (size_t)p * ROW];
            ss1 += snlPart[off + (size_t)(p + 1) * ROW];
        }
        pcnt[q][bin] = cs0 + cs1;
        psnl[q][bin] = ss0 + ss1;
    }
    __syncthreads();
    if (tid < NB) {
        scnt[tid] = (pcnt[0][tid] + pcnt[1][tid]) + (pcnt[2][tid] + pcnt[3][tid]);
        ssnl[tid] = (psnl[0][tid] + psnl[1][tid]) + (psnl[2][tid] + psnl[3][tid]);
    }
    __syncthreads();

    if (tid == 0) {
        int count = 0;
        #pragma unroll 8
        for (int i = 0; i < NB; ++i) count += scnt[i];
        float conf = 0.f;                // sum of nll where p >= 0.9
        #pragma unroll 8
        for (int i = CONF_BIN; i < NB; ++i) conf += ssnl[i];
        int k = (int)floorf((float)count * FRACTION_F);  // match jnp f32 math
        float sel;
        if (k == 0) {
            sel = conf;
        } else {
            int cum = 0;                 // count in bins strictly above boundary
            float csum = 0.f;
            int bin = NB - 1;
            int hh = 0;
            for (; bin >= 0; --bin) {
                hh = scnt[bin];
                if (cum + hh >= k) break;    // rank k-1 lies in this bin
                cum += hh;
                csum += ssnl[bin];
            }
            if (bin < 0) {
                sel = csum;              // safety (k < count always)
            } else if (bin >= CONF_BIN) {
                sel = conf;              // cutoff >= 0.9 -> union == {p>0.9}
            } else {
                float avg = ssnl[bin] / (float)max(hh, 1);
                sel = csum + (float)(k - cum) * avg;
            }
        }
        atomicAdd(out, sel * (1.0f / (float)(BB * (size_t)NPIX)));
    }
}

extern "C" void kernel_launch(void* const* d_in, const int* in_sizes, int n_in,
                              void* d_out, int out_size, void* d_ws, size_t ws_size,
                              hipStream_t stream) {
    const float* pred = (const float*)d_in[0];
    float* out = (float*)d_out;

    char* ws = (char*)d_ws;
    int*   cntPart = (int*)ws;
    float* snlPart = (float*)(ws + (size_t)NBLK1 * ROW * sizeof(int));

    st_pass1<<<NBLK1, T1, 0, stream>>>(pred, cntPart, snlPart, out);
    st_pass2<<<NROW, 384, 0, stream>>>(cntPart, snlPart, out);
}